// Round 11
// baseline (1167.961 us; speedup 1.0000x reference)
//
#include <hip/hip_runtime.h>
#include <hip/hip_bf16.h>

#define T_TOKENS 16384
#define HID 1024
#define NEXP 8
#define INTER 3584
#define PAIRS (2*T_TOKENS)
#define PAD_MAX (PAIRS + NEXP*256)   // 34816, multiple of 256

using f32x4    = __attribute__((ext_vector_type(4))) float;
using bfrag    = __attribute__((ext_vector_type(8))) short;
using float4_t = __attribute__((ext_vector_type(4))) float;
using ushort8_t = __attribute__((ext_vector_type(8))) unsigned short;

__device__ inline unsigned short f2bf(float f){
    unsigned u = __float_as_uint(f);
    u += 0x7FFFu + ((u >> 16) & 1u);          // RNE
    return (unsigned short)(u >> 16);
}

// async global -> LDS, 16B per lane, dest = wave base + lane*16 (linear)
__device__ inline void gload16(const unsigned short* g, unsigned short* l){
    __builtin_amdgcn_global_load_lds(
        (const __attribute__((address_space(1))) void*)g,
        (__attribute__((address_space(3))) void*)l, 16, 0, 0);
}

#define BAR_VM8() asm volatile("s_waitcnt vmcnt(8)\n\ts_barrier" ::: "memory")
#define BAR_VM4() asm volatile("s_waitcnt vmcnt(4)\n\ts_barrier" ::: "memory")
#define BAR_VM0() asm volatile("s_waitcnt vmcnt(0)\n\ts_barrier" ::: "memory")
#define BAR_PLAIN() asm volatile("s_barrier" ::: "memory")

// bijective XCD swizzle (m204)
__device__ inline int xcd_swz(int flat, int nwg){
    int q = nwg >> 3, r = nwg & 7;
    int xcd = flat & 7, idx = flat >> 3;
    return (xcd < r ? xcd*(q+1) : r*(q+1) + (xcd - r)*q) + idx;
}

// supertile decode
__device__ inline void st_decode(int sw, int nM, int nP, int STM,
                                 int& mt, int& p){
    int stSize = STM * nP;
    int st = sw / stSize;
    int rem = sw - st * stSize;
    int base = st * STM;
    int stM = (base + STM <= nM) ? STM : (nM - base);
    p  = rem / stM;
    mt = base + (rem - p * stM);
}

// ---------------- f32 -> bf16 conversion for the 3 weight tensors ----------------
__global__ __launch_bounds__(256) void conv3_kernel(
    const float* __restrict__ w1, const float* __restrict__ w3,
    const float* __restrict__ w2,
    unsigned short* __restrict__ w1b, unsigned short* __restrict__ w3b,
    unsigned short* __restrict__ w2b)
{
    const int n = NEXP * INTER * HID;
    const float* in = (blockIdx.y == 0) ? w1 : (blockIdx.y == 1) ? w3 : w2;
    unsigned short* out = (blockIdx.y == 0) ? w1b : (blockIdx.y == 1) ? w3b : w2b;
    int i0 = (blockIdx.x * 256 + threadIdx.x) * 8;
    int stride = gridDim.x * 256 * 8;
    for (int i = i0; i < n; i += stride){
        float4_t a = *reinterpret_cast<const float4_t*>(in + i);
        float4_t b = *reinterpret_cast<const float4_t*>(in + i + 4);
        ushort8_t o;
        o[0]=f2bf(a.x); o[1]=f2bf(a.y); o[2]=f2bf(a.z); o[3]=f2bf(a.w);
        o[4]=f2bf(b.x); o[5]=f2bf(b.y); o[6]=f2bf(b.z); o[7]=f2bf(b.w);
        *reinterpret_cast<ushort8_t*>(out + i) = o;
    }
}

// ---------------- router (+ fused x->bf16 conversion) ----------------
__global__ __launch_bounds__(256) void router_kernel(
    const float* __restrict__ x, const float* __restrict__ gw,
    int* __restrict__ topk_idx, float* __restrict__ topk_w,
    unsigned short* __restrict__ xb)
{
    int wave = threadIdx.x >> 6;
    int lane = threadIdx.x & 63;
    int t = blockIdx.x * 4 + wave;

    float acc[NEXP];
#pragma unroll
    for (int e = 0; e < NEXP; ++e) acc[e] = 0.f;

    const float* xr = x + (size_t)t * HID;
    for (int hb = 0; hb < HID; hb += 64){
        float xv = xr[hb + lane];
#pragma unroll
        for (int e = 0; e < NEXP; ++e)
            acc[e] += xv * gw[e * HID + hb + lane];
    }

    unsigned short* xbr = xb + (size_t)t * HID;
#pragma unroll
    for (int r = 0; r < 2; ++r){
        int c = (lane + r*64) * 8;
        float4_t va = *reinterpret_cast<const float4_t*>(xr + c);
        float4_t vb = *reinterpret_cast<const float4_t*>(xr + c + 4);
        ushort8_t o;
        o[0]=f2bf(va.x); o[1]=f2bf(va.y); o[2]=f2bf(va.z); o[3]=f2bf(va.w);
        o[4]=f2bf(vb.x); o[5]=f2bf(vb.y); o[6]=f2bf(vb.z); o[7]=f2bf(vb.w);
        *reinterpret_cast<ushort8_t*>(xbr + c) = o;
    }

#pragma unroll
    for (int e = 0; e < NEXP; ++e){
#pragma unroll
        for (int s = 32; s > 0; s >>= 1)
            acc[e] += __shfl_xor(acc[e], s, 64);
    }
    if (lane == 0){
        int e0 = 0; float m0 = acc[0];
#pragma unroll
        for (int e = 1; e < NEXP; ++e) if (acc[e] > m0){ m0 = acc[e]; e0 = e; }
        int e1 = -1; float m1 = -1e30f;
#pragma unroll
        for (int e = 0; e < NEXP; ++e) if (e != e0 && acc[e] > m1){ m1 = acc[e]; e1 = e; }
        float p1 = __expf(m1 - m0);
        float inv = 1.f / (1.f + p1);
        topk_idx[2*t]   = e0;
        topk_idx[2*t+1] = e1;
        topk_w[2*t]   = inv;
        topk_w[2*t+1] = p1 * inv;
    }
}

// ---------------- histogram ----------------
__global__ __launch_bounds__(256) void hist_kernel(
    const int* __restrict__ topk_idx, int* __restrict__ counts)
{
    __shared__ int h[NEXP];
    if (threadIdx.x < NEXP) h[threadIdx.x] = 0;
    __syncthreads();
    int i0 = blockIdx.x * 256 + threadIdx.x;
    for (int i = i0; i < PAIRS; i += gridDim.x * 256)
        atomicAdd(&h[topk_idx[i]], 1);
    __syncthreads();
    if (threadIdx.x < NEXP) atomicAdd(&counts[threadIdx.x], h[threadIdx.x]);
}

// prefix scan with 256-row padding (gemm2 uses 256-row M-tiles)
__global__ void scan_kernel(const int* __restrict__ counts, int* __restrict__ offp)
{
    if (threadIdx.x == 0 && blockIdx.x == 0){
        int s = 0;
        for (int e = 0; e < NEXP; ++e){
            offp[e] = s;
            s += (counts[e] + 255) & ~255;
        }
        offp[NEXP] = s;
    }
}

__global__ __launch_bounds__(128) void padfill_kernel(
    const int* __restrict__ counts, const int* __restrict__ offp,
    int* __restrict__ pair_token, float* __restrict__ pair_w)
{
    int e = blockIdx.x;
    int base = offp[e];
    int aligned = offp[e+1] - base;
    for (int s = counts[e] + threadIdx.x; s < aligned; s += 128){
        pair_token[base + s] = (base + s) & (T_TOKENS - 1);
        pair_w[base + s] = 0.f;
    }
}

// ---------------- scatter: block-batched range reservation ----------------
__global__ __launch_bounds__(256) void scatter_kernel(
    const int* __restrict__ topk_idx, const float* __restrict__ topk_w,
    const int* __restrict__ offp, int* __restrict__ cursors,
    int* __restrict__ pair_token, float* __restrict__ pair_w)
{
    __shared__ int hist[NEXP], base[NEXP], lcur[NEXP];
    int tid = threadIdx.x;
    if (tid < NEXP){ hist[tid] = 0; lcur[tid] = 0; }
    __syncthreads();

    int t = blockIdx.x * 256 + tid;
    int e0 = topk_idx[2*t], e1 = topk_idx[2*t + 1];
    atomicAdd(&hist[e0], 1);
    atomicAdd(&hist[e1], 1);
    __syncthreads();

    if (tid < NEXP) base[tid] = atomicAdd(&cursors[tid], hist[tid]);
    __syncthreads();

    int r0 = atomicAdd(&lcur[e0], 1);
    int r1 = atomicAdd(&lcur[e1], 1);
    int p0 = offp[e0] + base[e0] + r0;
    int p1 = offp[e1] + base[e1] + r1;
    pair_token[p0] = t;  pair_w[p0] = topk_w[2*t];
    pair_token[p1] = t;  pair_w[p1] = topk_w[2*t + 1];
}

// ---------------- fused w1/w3 GEMM + SwiGLU -> act (round-8 proven, unchanged) ----------------
__global__ __launch_bounds__(256) void gemm_act_kernel(
    const unsigned short* __restrict__ xb,
    const unsigned short* __restrict__ w1b,
    const unsigned short* __restrict__ w3b,
    const int* __restrict__ offp,
    const int* __restrict__ pair_token, const float* __restrict__ pair_w,
    unsigned short* __restrict__ act, int r0)
{
    int nP = gridDim.x, nM = gridDim.y;
    int sw = xcd_swz(blockIdx.y * nP + blockIdx.x, nP * nM);
    int mt, p;
    st_decode(sw, nM, nP, 8, mt, p);
    int by = mt, bx = p;

    int R = r0 + by * 128;
    if (R >= offp[NEXP]) return;
    int e = 0;
    while (offp[e+1] <= R) ++e;
    int icol0 = bx * 64;

    __shared__ alignas(16) unsigned short As0[128*64], As1[128*64];
    __shared__ alignas(16) unsigned short B10[64*64],  B11[64*64];
    __shared__ alignas(16) unsigned short B30[64*64],  B31[64*64];
    __shared__ int   toks[128];
    __shared__ float pws[128];

    int tid = threadIdx.x;
    if (tid < 128){
        toks[tid] = pair_token[R + tid];
        pws[tid]  = pair_w[R + tid];
    }
    __syncthreads();

    int w = tid >> 6, lane = tid & 63;
    int wm = w >> 1, wn = w & 1;
    int lr = lane >> 3;
    int l15 = lane & 15;
    int swz8 = ((lane & 7) ^ lr) * 8;

    size_t asrc[4];
#pragma unroll
    for (int i = 0; i < 4; ++i)
        asrc[i] = (size_t)toks[w*32 + i*8 + lr] * HID + swz8;

    const unsigned short* w1e = w1b + (size_t)e * INTER * HID;
    const unsigned short* w3e = w3b + (size_t)e * INTER * HID;
    size_t bsrc[2];
#pragma unroll
    for (int i = 0; i < 2; ++i)
        bsrc[i] = (size_t)(icol0 + w*16 + i*8 + lr) * HID + swz8;

    int ccol[2];
#pragma unroll
    for (int kk = 0; kk < 2; ++kk)
        ccol[kk] = (((kk*4 + (lane >> 4)) ^ (lane & 7)) * 8);

    f32x4 acc_h[4][2], acc_u[4][2];
#pragma unroll
    for (int m = 0; m < 4; ++m)
#pragma unroll
        for (int n = 0; n < 2; ++n){
            acc_h[m][n] = (f32x4){0.f,0.f,0.f,0.f};
            acc_u[m][n] = (f32x4){0.f,0.f,0.f,0.f};
        }

    auto stageT = [&](unsigned short* As, unsigned short* B1s, unsigned short* B3s, int t){
        int k0 = t * 64;
#pragma unroll
        for (int i = 0; i < 4; ++i) gload16(xb  + asrc[i] + k0, As  + (w*32 + i*8)*64);
#pragma unroll
        for (int i = 0; i < 2; ++i) gload16(w1e + bsrc[i] + k0, B1s + (w*16 + i*8)*64);
#pragma unroll
        for (int i = 0; i < 2; ++i) gload16(w3e + bsrc[i] + k0, B3s + (w*16 + i*8)*64);
    };

    auto computeT = [&](const unsigned short* As, const unsigned short* B1s, const unsigned short* B3s){
        __builtin_amdgcn_s_setprio(1);
#pragma unroll
        for (int kk = 0; kk < 2; ++kk){
            int cc = ccol[kk];
            bfrag a[4];
#pragma unroll
            for (int m = 0; m < 4; ++m)
                a[m] = *reinterpret_cast<const bfrag*>(&As[(wm*64 + m*16 + l15)*64 + cc]);
#pragma unroll
            for (int n = 0; n < 2; ++n){
                bfrag b1 = *reinterpret_cast<const bfrag*>(&B1s[(wn*32 + n*16 + l15)*64 + cc]);
                bfrag b3 = *reinterpret_cast<const bfrag*>(&B3s[(wn*32 + n*16 + l15)*64 + cc]);
#pragma unroll
                for (int m = 0; m < 4; ++m){
                    acc_h[m][n] = __builtin_amdgcn_mfma_f32_16x16x32_bf16(a[m], b1, acc_h[m][n], 0, 0, 0);
                    acc_u[m][n] = __builtin_amdgcn_mfma_f32_16x16x32_bf16(a[m], b3, acc_u[m][n], 0, 0, 0);
                }
            }
        }
        __builtin_amdgcn_s_setprio(0);
    };

    const int NT = HID / 64;   // 16
    stageT(As0, B10, B30, 0);
    stageT(As1, B11, B31, 1);
#pragma unroll 1
    for (int t = 0; t < NT - 2; t += 2){
        BAR_VM8();
        computeT(As0, B10, B30);
        BAR_PLAIN();
        stageT(As0, B10, B30, t + 2);
        BAR_VM8();
        computeT(As1, B11, B31);
        BAR_PLAIN();
        stageT(As1, B11, B31, t + 3);
    }
    BAR_VM8();
    computeT(As0, B10, B30);
    BAR_VM0();
    computeT(As1, B11, B31);

    size_t arow0 = (size_t)(by * 128) * INTER;
#pragma unroll
    for (int m = 0; m < 4; ++m){
#pragma unroll
        for (int n = 0; n < 2; ++n){
#pragma unroll
            for (int j = 0; j < 4; ++j){
                int rl = wm*64 + m*16 + (lane >> 4)*4 + j;
                float h = acc_h[m][n][j];
                float u = acc_u[m][n][j];
                float v = pws[rl] * h * u / (1.f + __expf(-h));
                int ic = icol0 + wn*32 + n*16 + l15;
                act[arow0 + (size_t)rl * INTER + ic] = f2bf(v);
            }
        }
    }
}

// ---------------- down-proj GEMM: 256x256 8-phase counted-vmcnt schedule ----------------
// BM=256 pair rows, BN=256 HID cols, BK=64, 512 threads (8 waves 2Mx4N),
// LDS 128KB = 2 K-tile buffers x (A 256x64 + B 256x64) bf16.
// Wave quadrants strided across halves: row = Mh*128 + wm*64 + mfl*16,
// col = Nh*128 + wn*32 + nf*16. Quadrant order (0,0),(1,0),(1,1),(0,1).
// One half-tile (2 gloads/thread) issued per phase; vmcnt(4) at phases 4,8.
__global__ __launch_bounds__(512) void gemm2_kernel(
    const unsigned short* __restrict__ act,
    const unsigned short* __restrict__ w2b,
    const int* __restrict__ offp,
    const int* __restrict__ pair_token,
    float* __restrict__ out, int r0)
{
    int nP = gridDim.x, nM = gridDim.y;
    int sw = xcd_swz(blockIdx.y * nP + blockIdx.x, nP * nM);
    int mt, p;
    st_decode(sw, nM, nP, 2, mt, p);
    int by = mt, bx = p;

    int R = r0 + by * 256;
    if (R >= offp[NEXP]) return;
    int e = 0;
    while (offp[e+1] <= R) ++e;
    int h0 = bx * 256;

    __shared__ alignas(16) unsigned short As0s[256*64], Bs0s[256*64];
    __shared__ alignas(16) unsigned short As1s[256*64], Bs1s[256*64];
    __shared__ int toks[256];

    int tid = threadIdx.x;
    if (tid < 256) toks[tid] = pair_token[R + tid];
    __syncthreads();

    int w = tid >> 6, lane = tid & 63;
    int wm = w >> 2, wn = w & 3;           // 2M x 4N
    int l15 = lane & 15;
    int sr = tid >> 3;                      // staging row 0..63
    int swzc8 = ((tid & 7) ^ (sr & 7)) * 8; // pre-swizzled source chunk (shorts)

    const unsigned short* w2e = w2b + (size_t)e * HID * INTER;
    size_t arow0 = (size_t)(by * 256) * INTER;

    // per-thread staging sources (half h adds h*128*INTER; tile adds t*64)
    size_t aoff0 = arow0 + (size_t)sr * INTER + swzc8;
    size_t aoff1 = aoff0 + (size_t)64 * INTER;
    size_t boff0 = (size_t)(h0 + sr) * INTER + swzc8;
    size_t boff1 = boff0 + (size_t)64 * INTER;

    int ccol[2];
#pragma unroll
    for (int kk = 0; kk < 2; ++kk)
        ccol[kk] = (((kk*4 + (lane >> 4)) ^ (lane & 7)) * 8);

    f32x4 acc[8][4];
#pragma unroll
    for (int m = 0; m < 8; ++m)
#pragma unroll
        for (int n = 0; n < 4; ++n)
            acc[m][n] = (f32x4){0.f,0.f,0.f,0.f};

    bfrag asub[4][2];   // current A quadrant frags (4 mfl x 2 kk)
    bfrag bsub[2][2];   // current B quadrant frags (2 nf x 2 kk)

    // stage one half-tile (2 gloads per thread)
    auto stA = [&](unsigned short* As, int h, int t){
        int kc = t * 64;
        gload16(act + aoff0 + (size_t)h*(128*INTER) + kc, As + h*8192 + tid*8);
        gload16(act + aoff1 + (size_t)h*(128*INTER) + kc, As + h*8192 + 4096 + tid*8);
    };
    auto stB = [&](unsigned short* Bs, int h, int t){
        int kc = t * 64;
        gload16(w2e + boff0 + (size_t)h*(128*INTER) + kc, Bs + h*8192 + tid*8);
        gload16(w2e + boff1 + (size_t)h*(128*INTER) + kc, Bs + h*8192 + 4096 + tid*8);
    };

    auto dsA = [&](const unsigned short* As, int Mh){
#pragma unroll
        for (int mfl = 0; mfl < 4; ++mfl)
#pragma unroll
            for (int kk = 0; kk < 2; ++kk)
                asub[mfl][kk] = *reinterpret_cast<const bfrag*>(
                    &As[(Mh*128 + wm*64 + mfl*16 + l15)*64 + ccol[kk]]);
    };
    auto dsB = [&](const unsigned short* Bs, int Nh){
#pragma unroll
        for (int nf = 0; nf < 2; ++nf)
#pragma unroll
            for (int kk = 0; kk < 2; ++kk)
                bsub[nf][kk] = *reinterpret_cast<const bfrag*>(
                    &Bs[(Nh*128 + wn*32 + nf*16 + l15)*64 + ccol[kk]]);
    };
    auto mma = [&](int Mh, int Nh){
        __builtin_amdgcn_s_setprio(1);
#pragma unroll
        for (int kk = 0; kk < 2; ++kk)
#pragma unroll
            for (int nf = 0; nf < 2; ++nf)
#pragma unroll
                for (int mfl = 0; mfl < 4; ++mfl)
                    acc[Mh*4+mfl][Nh*2+nf] = __builtin_amdgcn_mfma_f32_16x16x32_bf16(
                        asub[mfl][kk], bsub[nf][kk], acc[Mh*4+mfl][Nh*2+nf], 0, 0, 0);
        __builtin_amdgcn_s_setprio(0);
    };

    const int NT = INTER / 64;   // 56 (even)

    // prologue: mirror steady-state issue slots ph3..ph8
    stB(Bs0s, 0, 0);   // B0(0)
    stA(As0s, 1, 0);   // A1(0)
    stA(As0s, 0, 0);   // A0(0)
    stB(Bs0s, 1, 0);   // B1(0)
    stB(Bs1s, 0, 1);   // B0(1)
    stA(As1s, 1, 1);   // A1(1)
    BAR_VM4();         // tile 0 fully arrived; B0(1),A1(1) in flight

#pragma unroll 1
    for (int i = 0; i < NT/2 - 1; ++i){
        int t1 = 2*i + 1, t2 = 2*i + 2, t3 = 2*i + 3;
        // ph1: X0 quadrant (0,0)
        dsA(As0s, 0); dsB(Bs0s, 0);
        stA(As1s, 0, t1);
        BAR_PLAIN(); mma(0, 0); BAR_PLAIN();
        // ph2: (1,0) — reuse bsub
        dsA(As0s, 1);
        stB(Bs1s, 1, t1);
        BAR_PLAIN(); mma(1, 0); BAR_PLAIN();
        // ph3: (1,1) — reuse asub
        dsB(Bs0s, 1);
        stB(Bs0s, 0, t2);
        BAR_PLAIN(); mma(1, 1); BAR_PLAIN();
        // ph4: (0,1) — reuse bsub; wait: tile t1 complete
        dsA(As0s, 0);
        stA(As0s, 1, t2);
        BAR_VM4(); mma(0, 1); BAR_PLAIN();
        // ph5: X1 quadrant (0,0)
        dsA(As1s, 0); dsB(Bs1s, 0);
        stA(As0s, 0, t2);
        BAR_PLAIN(); mma(0, 0); BAR_PLAIN();
        // ph6: (1,0)
        dsA(As1s, 1);
        stB(Bs0s, 1, t2);
        BAR_PLAIN(); mma(1, 0); BAR_PLAIN();
        // ph7: (1,1)
        dsB(Bs1s, 1);
        stB(Bs1s, 0, t3);
        BAR_PLAIN(); mma(1, 1); BAR_PLAIN();
        // ph8: (0,1); wait: tile t2 complete
        dsA(As1s, 0);
        stA(As1s, 1, t3);
        BAR_VM4(); mma(0, 1); BAR_PLAIN();
    }

    // tail: tiles NT-2 (X0), NT-1 (X1); only ph1/ph2 issue (last halves of NT-1)
    dsA(As0s, 0); dsB(Bs0s, 0);
    stA(As1s, 0, NT-1);
    BAR_PLAIN(); mma(0, 0); BAR_PLAIN();
    dsA(As0s, 1);
    stB(Bs1s, 1, NT-1);
    BAR_PLAIN(); mma(1, 0); BAR_PLAIN();
    dsB(Bs0s, 1);
    BAR_PLAIN(); mma(1, 1); BAR_PLAIN();
    dsA(As0s, 0);
    BAR_VM0(); mma(0, 1); BAR_PLAIN();
    dsA(As1s, 0); dsB(Bs1s, 0);
    BAR_PLAIN(); mma(0, 0); BAR_PLAIN();
    dsA(As1s, 1);
    BAR_PLAIN(); mma(1, 0); BAR_PLAIN();
    dsB(Bs1s, 1);
    BAR_PLAIN(); mma(1, 1); BAR_PLAIN();
    dsA(As1s, 0);
    BAR_PLAIN(); mma(0, 1); BAR_PLAIN();

    // epilogue: atomic accumulate (weight folded into act)
#pragma unroll
    for (int m = 0; m < 8; ++m){
#pragma unroll
        for (int n = 0; n < 4; ++n){
#pragma unroll
            for (int j = 0; j < 4; ++j){
                int rl = (m >> 2)*128 + wm*64 + (m & 3)*16 + (lane >> 4)*4 + j;
                int hc = h0 + (n >> 1)*128 + wn*32 + (n & 1)*16 + l15;
                atomicAdd(&out[(size_t)toks[rl] * HID + hc], acc[m][n][j]);
            }
        }
    }
}

extern "C" void kernel_launch(void* const* d_in, const int* in_sizes, int n_in,
                              void* d_out, int out_size, void* d_ws, size_t ws_size,
                              hipStream_t stream)
{
    const float* x  = (const float*)d_in[0];
    const float* gw = (const float*)d_in[1];
    const float* w1 = (const float*)d_in[2];
    const float* w3 = (const float*)d_in[3];
    const float* w2 = (const float*)d_in[4];
    float* out = (float*)d_out;

    char* ws = (char*)d_ws;
    size_t off = 0;
    auto bump = [&](size_t bytes) -> void* {
        void* p = ws + off;
        off = (off + bytes + 255) & ~(size_t)255;
        return p;
    };
    int*   counts     = (int*)bump(32);
    int*   cursors    = (int*)bump(32);
    int*   offp       = (int*)bump(64);
    int*   topk_idx   = (int*)bump((size_t)PAIRS * 4);
    float* topk_w     = (float*)bump((size_t)PAIRS * 4);
    int*   pair_token = (int*)bump((size_t)PAD_MAX * 4);
    float* pair_w     = (float*)bump((size_t)PAD_MAX * 4);
    unsigned short* xb  = (unsigned short*)bump((size_t)T_TOKENS * HID * 2);
    unsigned short* w1b = (unsigned short*)bump((size_t)NEXP * INTER * HID * 2);
    unsigned short* w3b = (unsigned short*)bump((size_t)NEXP * INTER * HID * 2);
    unsigned short* w2b = (unsigned short*)bump((size_t)NEXP * HID * INTER * 2);
    unsigned short* act = (unsigned short*)(ws + off);

    size_t rem = (ws_size > off) ? (ws_size - off) : 0;
    int RC = (int)(rem / ((size_t)INTER * 2));
    RC &= ~255;
    if (RC > PAD_MAX) RC = PAD_MAX;
    if (RC < 256) RC = 256;
    int nchunks = (PAD_MAX + RC - 1) / RC;

    hipMemsetAsync(d_out, 0, (size_t)T_TOKENS * HID * 4, stream);
    hipMemsetAsync(ws, 0, 1024, stream);

    conv3_kernel<<<dim3(768, 3), 256, 0, stream>>>(w1, w3, w2, w1b, w3b, w2b);

    router_kernel<<<T_TOKENS/4, 256, 0, stream>>>(x, gw, topk_idx, topk_w, xb);
    hist_kernel<<<64, 256, 0, stream>>>(topk_idx, counts);
    scan_kernel<<<1, 64, 0, stream>>>(counts, offp);
    padfill_kernel<<<NEXP, 128, 0, stream>>>(counts, offp, pair_token, pair_w);
    scatter_kernel<<<T_TOKENS/256, 256, 0, stream>>>(topk_idx, topk_w, offp, cursors,
                                                     pair_token, pair_w);

    for (int c = 0; c < nchunks; ++c){
        int r0 = c * RC;
        gemm_act_kernel<<<dim3(INTER/64, RC/128), 256, 0, stream>>>(
            xb, w1b, w3b, offp, pair_token, pair_w, act, r0);
        gemm2_kernel<<<dim3(HID/256, RC/256), 512, 0, stream>>>(
            act, w2b, offp, pair_token, out, r0);
    }
}

// Round 12
// 1089.424 us; speedup vs baseline: 1.0721x; 1.0721x over previous
//
#include <hip/hip_runtime.h>
#include <hip/hip_bf16.h>

#define T_TOKENS 16384
#define HID 1024
#define NEXP 8
#define INTER 3584
#define PAIRS (2*T_TOKENS)
#define PAD_MAX (PAIRS + NEXP*256)   // 34816, multiple of 256

using f32x4    = __attribute__((ext_vector_type(4))) float;
using bfrag    = __attribute__((ext_vector_type(8))) short;
using float4_t = __attribute__((ext_vector_type(4))) float;
using ushort8_t = __attribute__((ext_vector_type(8))) unsigned short;

__device__ inline unsigned short f2bf(float f){
    unsigned u = __float_as_uint(f);
    u += 0x7FFFu + ((u >> 16) & 1u);          // RNE
    return (unsigned short)(u >> 16);
}

// async global -> LDS, 16B per lane, dest = wave base + lane*16 (linear)
__device__ inline void gload16(const unsigned short* g, unsigned short* l){
    __builtin_amdgcn_global_load_lds(
        (const __attribute__((address_space(1))) void*)g,
        (__attribute__((address_space(3))) void*)l, 16, 0, 0);
}

#define BAR_VM8() asm volatile("s_waitcnt vmcnt(8)\n\ts_barrier" ::: "memory")
#define BAR_VM4() asm volatile("s_waitcnt vmcnt(4)\n\ts_barrier" ::: "memory")
#define BAR_VM0() asm volatile("s_waitcnt vmcnt(0)\n\ts_barrier" ::: "memory")
#define BAR_PLAIN() asm volatile("s_barrier" ::: "memory")

// bijective XCD swizzle (m204)
__device__ inline int xcd_swz(int flat, int nwg){
    int q = nwg >> 3, r = nwg & 7;
    int xcd = flat & 7, idx = flat >> 3;
    return (xcd < r ? xcd*(q+1) : r*(q+1) + (xcd - r)*q) + idx;
}

// supertile decode
__device__ inline void st_decode(int sw, int nM, int nP, int STM,
                                 int& mt, int& p){
    int stSize = STM * nP;
    int st = sw / stSize;
    int rem = sw - st * stSize;
    int base = st * STM;
    int stM = (base + STM <= nM) ? STM : (nM - base);
    p  = rem / stM;
    mt = base + (rem - p * stM);
}

// ---------------- f32 -> bf16 conversion for the 3 weight tensors ----------------
__global__ __launch_bounds__(256) void conv3_kernel(
    const float* __restrict__ w1, const float* __restrict__ w3,
    const float* __restrict__ w2,
    unsigned short* __restrict__ w1b, unsigned short* __restrict__ w3b,
    unsigned short* __restrict__ w2b)
{
    const int n = NEXP * INTER * HID;
    const float* in = (blockIdx.y == 0) ? w1 : (blockIdx.y == 1) ? w3 : w2;
    unsigned short* out = (blockIdx.y == 0) ? w1b : (blockIdx.y == 1) ? w3b : w2b;
    int i0 = (blockIdx.x * 256 + threadIdx.x) * 8;
    int stride = gridDim.x * 256 * 8;
    for (int i = i0; i < n; i += stride){
        float4_t a = *reinterpret_cast<const float4_t*>(in + i);
        float4_t b = *reinterpret_cast<const float4_t*>(in + i + 4);
        ushort8_t o;
        o[0]=f2bf(a.x); o[1]=f2bf(a.y); o[2]=f2bf(a.z); o[3]=f2bf(a.w);
        o[4]=f2bf(b.x); o[5]=f2bf(b.y); o[6]=f2bf(b.z); o[7]=f2bf(b.w);
        *reinterpret_cast<ushort8_t*>(out + i) = o;
    }
}

// ---------------- router (+ fused x->bf16 conversion) ----------------
__global__ __launch_bounds__(256) void router_kernel(
    const float* __restrict__ x, const float* __restrict__ gw,
    int* __restrict__ topk_idx, float* __restrict__ topk_w,
    unsigned short* __restrict__ xb)
{
    int wave = threadIdx.x >> 6;
    int lane = threadIdx.x & 63;
    int t = blockIdx.x * 4 + wave;

    float acc[NEXP];
#pragma unroll
    for (int e = 0; e < NEXP; ++e) acc[e] = 0.f;

    const float* xr = x + (size_t)t * HID;
    for (int hb = 0; hb < HID; hb += 64){
        float xv = xr[hb + lane];
#pragma unroll
        for (int e = 0; e < NEXP; ++e)
            acc[e] += xv * gw[e * HID + hb + lane];
    }

    unsigned short* xbr = xb + (size_t)t * HID;
#pragma unroll
    for (int r = 0; r < 2; ++r){
        int c = (lane + r*64) * 8;
        float4_t va = *reinterpret_cast<const float4_t*>(xr + c);
        float4_t vb = *reinterpret_cast<const float4_t*>(xr + c + 4);
        ushort8_t o;
        o[0]=f2bf(va.x); o[1]=f2bf(va.y); o[2]=f2bf(va.z); o[3]=f2bf(va.w);
        o[4]=f2bf(vb.x); o[5]=f2bf(vb.y); o[6]=f2bf(vb.z); o[7]=f2bf(vb.w);
        *reinterpret_cast<ushort8_t*>(xbr + c) = o;
    }

#pragma unroll
    for (int e = 0; e < NEXP; ++e){
#pragma unroll
        for (int s = 32; s > 0; s >>= 1)
            acc[e] += __shfl_xor(acc[e], s, 64);
    }
    if (lane == 0){
        int e0 = 0; float m0 = acc[0];
#pragma unroll
        for (int e = 1; e < NEXP; ++e) if (acc[e] > m0){ m0 = acc[e]; e0 = e; }
        int e1 = -1; float m1 = -1e30f;
#pragma unroll
        for (int e = 0; e < NEXP; ++e) if (e != e0 && acc[e] > m1){ m1 = acc[e]; e1 = e; }
        float p1 = __expf(m1 - m0);
        float inv = 1.f / (1.f + p1);
        topk_idx[2*t]   = e0;
        topk_idx[2*t+1] = e1;
        topk_w[2*t]   = inv;
        topk_w[2*t+1] = p1 * inv;
    }
}

// ---------------- histogram ----------------
__global__ __launch_bounds__(256) void hist_kernel(
    const int* __restrict__ topk_idx, int* __restrict__ counts)
{
    __shared__ int h[NEXP];
    if (threadIdx.x < NEXP) h[threadIdx.x] = 0;
    __syncthreads();
    int i0 = blockIdx.x * 256 + threadIdx.x;
    for (int i = i0; i < PAIRS; i += gridDim.x * 256)
        atomicAdd(&h[topk_idx[i]], 1);
    __syncthreads();
    if (threadIdx.x < NEXP) atomicAdd(&counts[threadIdx.x], h[threadIdx.x]);
}

// prefix scan with 256-row padding (gemm_act uses 256-row M-tiles)
__global__ void scan_kernel(const int* __restrict__ counts, int* __restrict__ offp)
{
    if (threadIdx.x == 0 && blockIdx.x == 0){
        int s = 0;
        for (int e = 0; e < NEXP; ++e){
            offp[e] = s;
            s += (counts[e] + 255) & ~255;
        }
        offp[NEXP] = s;
    }
}

__global__ __launch_bounds__(128) void padfill_kernel(
    const int* __restrict__ counts, const int* __restrict__ offp,
    int* __restrict__ pair_token, float* __restrict__ pair_w)
{
    int e = blockIdx.x;
    int base = offp[e];
    int aligned = offp[e+1] - base;
    for (int s = counts[e] + threadIdx.x; s < aligned; s += 128){
        pair_token[base + s] = (base + s) & (T_TOKENS - 1);
        pair_w[base + s] = 0.f;
    }
}

// ---------------- scatter: block-batched range reservation ----------------
__global__ __launch_bounds__(256) void scatter_kernel(
    const int* __restrict__ topk_idx, const float* __restrict__ topk_w,
    const int* __restrict__ offp, int* __restrict__ cursors,
    int* __restrict__ pair_token, float* __restrict__ pair_w)
{
    __shared__ int hist[NEXP], base[NEXP], lcur[NEXP];
    int tid = threadIdx.x;
    if (tid < NEXP){ hist[tid] = 0; lcur[tid] = 0; }
    __syncthreads();

    int t = blockIdx.x * 256 + tid;
    int e0 = topk_idx[2*t], e1 = topk_idx[2*t + 1];
    atomicAdd(&hist[e0], 1);
    atomicAdd(&hist[e1], 1);
    __syncthreads();

    if (tid < NEXP) base[tid] = atomicAdd(&cursors[tid], hist[tid]);
    __syncthreads();

    int r0 = atomicAdd(&lcur[e0], 1);
    int r1 = atomicAdd(&lcur[e1], 1);
    int p0 = offp[e0] + base[e0] + r0;
    int p1 = offp[e1] + base[e1] + r1;
    pair_token[p0] = t;  pair_w[p0] = topk_w[2*t];
    pair_token[p1] = t;  pair_w[p1] = topk_w[2*t + 1];
}

// ---------------- fused w1/w3 GEMM + SwiGLU -> act: 256x128 8-phase ----------------
// BM=256 pair rows, BN=128 INTER cols (h AND u streams), BK=64, 512 thr (8 waves
// 2Mx4N). LDS 128KB = 2 bufs x (A 256x64 + B1 128x64 + B3 128x64). Quadrants =
// (Mh, stream): order (0,h),(1,h),(1,u),(0,u). One issue-unit (2 gloads/thread)
// per phase; vmcnt(4) at phases 4 and 8 (identical FIFO arithmetic to the
// round-11-verified gemm2 schedule; unit map Bh<->B-h0, A1<->A-h1, A0<->A-h0,
// Bu<->B-h1). Two barriers separate every LDS overwrite from its last reader.
__global__ __launch_bounds__(512) void gemm_act_kernel(
    const unsigned short* __restrict__ xb,
    const unsigned short* __restrict__ w1b,
    const unsigned short* __restrict__ w3b,
    const int* __restrict__ offp,
    const int* __restrict__ pair_token, const float* __restrict__ pair_w,
    unsigned short* __restrict__ act, int r0)
{
    int nP = gridDim.x, nM = gridDim.y;
    int sw = xcd_swz(blockIdx.y * nP + blockIdx.x, nP * nM);
    int mt, p;
    st_decode(sw, nM, nP, 4, mt, p);
    int by = mt, bx = p;

    int R = r0 + by * 256;
    if (R >= offp[NEXP]) return;
    int e = 0;
    while (offp[e+1] <= R) ++e;
    int icol0 = bx * 128;

    __shared__ alignas(16) unsigned short As0s[256*64], B1s0[128*64], B3s0[128*64];
    __shared__ alignas(16) unsigned short As1s[256*64], B1s1[128*64], B3s1[128*64];
    __shared__ int   toks[256];
    __shared__ float pws[256];

    int tid = threadIdx.x;
    if (tid < 256){
        toks[tid] = pair_token[R + tid];
        pws[tid]  = pair_w[R + tid];
    }
    __syncthreads();

    int w = tid >> 6, lane = tid & 63;
    int wm = w >> 2, wn = w & 3;            // 2M x 4N
    int l15 = lane & 15;
    int sr = tid >> 3;                       // staging row 0..63
    int swzc8 = ((tid & 7) ^ (sr & 7)) * 8;  // pre-swizzled source chunk (shorts)

    const unsigned short* w1e = w1b + (size_t)e * INTER * HID;
    const unsigned short* w3e = w3b + (size_t)e * INTER * HID;

    // gathered A sources: [half][gload] ; A half h, gload g covers rows h*128+g*64+sr
    size_t asrc[2][2];
#pragma unroll
    for (int h = 0; h < 2; ++h)
#pragma unroll
        for (int g = 0; g < 2; ++g)
            asrc[h][g] = (size_t)toks[h*128 + g*64 + sr] * HID + swzc8;
    // B sources (dense INTER rows): gload g covers rows icol0+g*64+sr
    size_t boff[2];
#pragma unroll
    for (int g = 0; g < 2; ++g)
        boff[g] = (size_t)(icol0 + g*64 + sr) * HID + swzc8;

    int ccol[2];
#pragma unroll
    for (int kk = 0; kk < 2; ++kk)
        ccol[kk] = (((kk*4 + (lane >> 4)) ^ (lane & 7)) * 8);

    f32x4 acc[8][4];   // [Mh*4+mfl][S*2+nf], S=0:h(w1), S=1:u(w3)
#pragma unroll
    for (int m = 0; m < 8; ++m)
#pragma unroll
        for (int n = 0; n < 4; ++n)
            acc[m][n] = (f32x4){0.f,0.f,0.f,0.f};

    bfrag asub[4][2];   // current A quadrant frags (4 mfl x 2 kk)
    bfrag bsub[2][2];   // current B quadrant frags (2 nf x 2 kk)

    // issue-units (2 gloads each)
    auto stA = [&](unsigned short* As, int h, int t){
        int kc = t * 64;
        gload16(xb + asrc[h][0] + kc, As + h*8192 + tid*8);
        gload16(xb + asrc[h][1] + kc, As + h*8192 + 4096 + tid*8);
    };
    auto stBh = [&](unsigned short* B1s, int t){
        int kc = t * 64;
        gload16(w1e + boff[0] + kc, B1s + tid*8);
        gload16(w1e + boff[1] + kc, B1s + 4096 + tid*8);
    };
    auto stBu = [&](unsigned short* B3s, int t){
        int kc = t * 64;
        gload16(w3e + boff[0] + kc, B3s + tid*8);
        gload16(w3e + boff[1] + kc, B3s + 4096 + tid*8);
    };

    auto dsA = [&](const unsigned short* As, int Mh){
#pragma unroll
        for (int mfl = 0; mfl < 4; ++mfl)
#pragma unroll
            for (int kk = 0; kk < 2; ++kk)
                asub[mfl][kk] = *reinterpret_cast<const bfrag*>(
                    &As[(Mh*128 + wm*64 + mfl*16 + l15)*64 + ccol[kk]]);
    };
    auto dsB = [&](const unsigned short* Bs){
#pragma unroll
        for (int nf = 0; nf < 2; ++nf)
#pragma unroll
            for (int kk = 0; kk < 2; ++kk)
                bsub[nf][kk] = *reinterpret_cast<const bfrag*>(
                    &Bs[(wn*32 + nf*16 + l15)*64 + ccol[kk]]);
    };
    auto mma = [&](int Mh, int S){
        __builtin_amdgcn_s_setprio(1);
#pragma unroll
        for (int kk = 0; kk < 2; ++kk)
#pragma unroll
            for (int nf = 0; nf < 2; ++nf)
#pragma unroll
                for (int mfl = 0; mfl < 4; ++mfl)
                    acc[Mh*4+mfl][S*2+nf] = __builtin_amdgcn_mfma_f32_16x16x32_bf16(
                        asub[mfl][kk], bsub[nf][kk], acc[Mh*4+mfl][S*2+nf], 0, 0, 0);
        __builtin_amdgcn_s_setprio(0);
    };

    const int NT = HID / 64;   // 16 (even)

    // prologue: mirror steady-state issue slots (tile0 complete + 2 units of tile1)
    stBh(B1s0, 0);
    stA(As0s, 1, 0);
    stA(As0s, 0, 0);
    stBu(B3s0, 0);
    stBh(B1s1, 1);
    stA(As1s, 1, 1);
    BAR_VM4();         // tile 0 fully arrived; Bh(1), A-h1(1) in flight

#pragma unroll 1
    for (int i = 0; i < NT/2 - 1; ++i){
        int t1 = 2*i + 1, t2 = 2*i + 2, t3 = 2*i + 3;
        // ph1: X0 (Mh0, h)
        dsA(As0s, 0); dsB(B1s0);
        stA(As1s, 0, t1);
        BAR_PLAIN(); mma(0, 0); BAR_PLAIN();
        // ph2: (Mh1, h) — reuse bsub
        dsA(As0s, 1);
        stBu(B3s1, t1);
        BAR_PLAIN(); mma(1, 0); BAR_PLAIN();
        // ph3: (Mh1, u) — reuse asub
        dsB(B3s0);
        stBh(B1s0, t2);
        BAR_PLAIN(); mma(1, 1); BAR_PLAIN();
        // ph4: (Mh0, u) — reuse bsub; wait: tile t1 complete
        dsA(As0s, 0);
        stA(As0s, 1, t2);
        BAR_VM4(); mma(0, 1); BAR_PLAIN();
        // ph5: X1 (Mh0, h)
        dsA(As1s, 0); dsB(B1s1);
        stA(As0s, 0, t2);
        BAR_PLAIN(); mma(0, 0); BAR_PLAIN();
        // ph6: (Mh1, h)
        dsA(As1s, 1);
        stBu(B3s0, t2);
        BAR_PLAIN(); mma(1, 0); BAR_PLAIN();
        // ph7: (Mh1, u)
        dsB(B3s1);
        stBh(B1s1, t3);
        BAR_PLAIN(); mma(1, 1); BAR_PLAIN();
        // ph8: (Mh0, u); wait: tile t2 complete
        dsA(As1s, 0);
        stA(As1s, 1, t3);
        BAR_VM4(); mma(0, 1); BAR_PLAIN();
    }

    // tail: tiles NT-2 (X0), NT-1 (X1)
    dsA(As0s, 0); dsB(B1s0);
    stA(As1s, 0, NT-1);
    BAR_PLAIN(); mma(0, 0); BAR_PLAIN();
    dsA(As0s, 1);
    stBu(B3s1, NT-1);
    BAR_PLAIN(); mma(1, 0); BAR_PLAIN();
    dsB(B3s0);
    BAR_PLAIN(); mma(1, 1); BAR_PLAIN();
    dsA(As0s, 0);
    BAR_VM0(); mma(0, 1); BAR_PLAIN();
    dsA(As1s, 0); dsB(B1s1);
    BAR_PLAIN(); mma(0, 0); BAR_PLAIN();
    dsA(As1s, 1);
    BAR_PLAIN(); mma(1, 0); BAR_PLAIN();
    dsB(B3s1);
    BAR_PLAIN(); mma(1, 1); BAR_PLAIN();
    dsA(As1s, 0);
    BAR_PLAIN(); mma(0, 1); BAR_PLAIN();

    // epilogue: act = pair_w * silu(h) * u  (h=acc[m][nf], u=acc[m][2+nf])
    size_t arow0 = (size_t)(by * 256) * INTER;
#pragma unroll
    for (int m = 0; m < 8; ++m){
#pragma unroll
        for (int nf = 0; nf < 2; ++nf){
#pragma unroll
            for (int j = 0; j < 4; ++j){
                int rl = (m >> 2)*128 + wm*64 + (m & 3)*16 + (lane >> 4)*4 + j;
                float h = acc[m][nf][j];
                float u = acc[m][2 + nf][j];
                float v = pws[rl] * h * u / (1.f + __expf(-h));
                int ic = icol0 + wn*32 + nf*16 + l15;
                act[arow0 + (size_t)rl * INTER + ic] = f2bf(v);
            }
        }
    }
}

// ---------------- down-proj GEMM (round-10 proven 2-phase 128x128) ----------------
__global__ __launch_bounds__(256) void gemm2_kernel(
    const unsigned short* __restrict__ act,
    const unsigned short* __restrict__ w2b,
    const int* __restrict__ offp,
    const int* __restrict__ pair_token,
    float* __restrict__ out, int r0)
{
    int nP = gridDim.x, nM = gridDim.y;
    int sw = xcd_swz(blockIdx.y * nP + blockIdx.x, nP * nM);
    int mt, p;
    st_decode(sw, nM, nP, 4, mt, p);
    int by = mt, bx = p;

    int R = r0 + by * 128;
    if (R >= offp[NEXP]) return;
    int e = 0;
    while (offp[e+1] <= R) ++e;
    int h0 = bx * 128;

    __shared__ alignas(16) unsigned short As0[128*64], As1[128*64];
    __shared__ alignas(16) unsigned short Bs0[128*64], Bs1[128*64];
    __shared__ int toks[128];

    int tid = threadIdx.x;
    if (tid < 128) toks[tid] = pair_token[R + tid];
    __syncthreads();

    int w = tid >> 6, lane = tid & 63;
    int wm = w >> 1, wn = w & 1;
    int lr = lane >> 3;
    int l15 = lane & 15;
    int swz8 = ((lane & 7) ^ lr) * 8;

    const unsigned short* w2e = w2b + (size_t)e * HID * INTER;
    size_t arow0 = (size_t)(by * 128) * INTER;

    size_t asrc[4], bsrc[4];
#pragma unroll
    for (int i = 0; i < 4; ++i){
        asrc[i] = arow0 + (size_t)(w*32 + i*8 + lr) * INTER + swz8;
        bsrc[i] = (size_t)(h0 + w*32 + i*8 + lr) * INTER + swz8;
    }

    int ccol[2];
#pragma unroll
    for (int kk = 0; kk < 2; ++kk)
        ccol[kk] = (((kk*4 + (lane >> 4)) ^ (lane & 7)) * 8);

    f32x4 acc[4][4];
#pragma unroll
    for (int m = 0; m < 4; ++m)
#pragma unroll
        for (int n = 0; n < 4; ++n)
            acc[m][n] = (f32x4){0.f,0.f,0.f,0.f};

    auto stageT = [&](unsigned short* As, unsigned short* Bs, int t){
        int kc = t * 64;
#pragma unroll
        for (int i = 0; i < 4; ++i) gload16(act + asrc[i] + kc, As + (w*32 + i*8)*64);
#pragma unroll
        for (int i = 0; i < 4; ++i) gload16(w2e + bsrc[i] + kc, Bs + (w*32 + i*8)*64);
    };

    auto computeT = [&](const unsigned short* As, const unsigned short* Bs){
        __builtin_amdgcn_s_setprio(1);
#pragma unroll
        for (int kk = 0; kk < 2; ++kk){
            int cc = ccol[kk];
            bfrag a[4];
#pragma unroll
            for (int m = 0; m < 4; ++m)
                a[m] = *reinterpret_cast<const bfrag*>(&As[(wm*64 + m*16 + l15)*64 + cc]);
#pragma unroll
            for (int n = 0; n < 4; ++n){
                bfrag b = *reinterpret_cast<const bfrag*>(&Bs[(wn*64 + n*16 + l15)*64 + cc]);
#pragma unroll
                for (int m = 0; m < 4; ++m)
                    acc[m][n] = __builtin_amdgcn_mfma_f32_16x16x32_bf16(a[m], b, acc[m][n], 0, 0, 0);
            }
        }
        __builtin_amdgcn_s_setprio(0);
    };

    const int NT = INTER / 64;   // 56 (even)
    stageT(As0, Bs0, 0);
    stageT(As1, Bs1, 1);
#pragma unroll 1
    for (int t = 0; t < NT - 2; t += 2){
        BAR_VM8();
        computeT(As0, Bs0);
        BAR_PLAIN();
        stageT(As0, Bs0, t + 2);
        BAR_VM8();
        computeT(As1, Bs1);
        BAR_PLAIN();
        stageT(As1, Bs1, t + 3);
    }
    BAR_VM8();
    computeT(As0, Bs0);
    BAR_VM0();
    computeT(As1, Bs1);

#pragma unroll
    for (int m = 0; m < 4; ++m){
#pragma unroll
        for (int n = 0; n < 4; ++n){
#pragma unroll
            for (int j = 0; j < 4; ++j){
                int rl = wm*64 + m*16 + (lane >> 4)*4 + j;
                int hc = h0 + wn*64 + n*16 + l15;
                atomicAdd(&out[(size_t)toks[rl] * HID + hc], acc[m][n][j]);
            }
        }
    }
}

extern "C" void kernel_launch(void* const* d_in, const int* in_sizes, int n_in,
                              void* d_out, int out_size, void* d_ws, size_t ws_size,
                              hipStream_t stream)
{
    const float* x  = (const float*)d_in[0];
    const float* gw = (const float*)d_in[1];
    const float* w1 = (const float*)d_in[2];
    const float* w3 = (const float*)d_in[3];
    const float* w2 = (const float*)d_in[4];
    float* out = (float*)d_out;

    char* ws = (char*)d_ws;
    size_t off = 0;
    auto bump = [&](size_t bytes) -> void* {
        void* p = ws + off;
        off = (off + bytes + 255) & ~(size_t)255;
        return p;
    };
    int*   counts     = (int*)bump(32);
    int*   cursors    = (int*)bump(32);
    int*   offp       = (int*)bump(64);
    int*   topk_idx   = (int*)bump((size_t)PAIRS * 4);
    float* topk_w     = (float*)bump((size_t)PAIRS * 4);
    int*   pair_token = (int*)bump((size_t)PAD_MAX * 4);
    float* pair_w     = (float*)bump((size_t)PAD_MAX * 4);
    unsigned short* xb  = (unsigned short*)bump((size_t)T_TOKENS * HID * 2);
    unsigned short* w1b = (unsigned short*)bump((size_t)NEXP * INTER * HID * 2);
    unsigned short* w3b = (unsigned short*)bump((size_t)NEXP * INTER * HID * 2);
    unsigned short* w2b = (unsigned short*)bump((size_t)NEXP * HID * INTER * 2);
    unsigned short* act = (unsigned short*)(ws + off);

    size_t rem = (ws_size > off) ? (ws_size - off) : 0;
    int RC = (int)(rem / ((size_t)INTER * 2));
    RC &= ~255;
    if (RC > PAD_MAX) RC = PAD_MAX;
    if (RC < 256) RC = 256;
    int nchunks = (PAD_MAX + RC - 1) / RC;

    hipMemsetAsync(d_out, 0, (size_t)T_TOKENS * HID * 4, stream);
    hipMemsetAsync(ws, 0, 1024, stream);

    conv3_kernel<<<dim3(768, 3), 256, 0, stream>>>(w1, w3, w2, w1b, w3b, w2b);

    router_kernel<<<T_TOKENS/4, 256, 0, stream>>>(x, gw, topk_idx, topk_w, xb);
    hist_kernel<<<64, 256, 0, stream>>>(topk_idx, counts);
    scan_kernel<<<1, 64, 0, stream>>>(counts, offp);
    padfill_kernel<<<NEXP, 128, 0, stream>>>(counts, offp, pair_token, pair_w);
    scatter_kernel<<<T_TOKENS/256, 256, 0, stream>>>(topk_idx, topk_w, offp, cursors,
                                                     pair_token, pair_w);

    for (int c = 0; c < nchunks; ++c){
        int r0 = c * RC;
        gemm_act_kernel<<<dim3(INTER/128, RC/256), 512, 0, stream>>>(
            xb, w1b, w3b, offp, pair_token, pair_w, act, r0);
        gemm2_kernel<<<dim3(HID/128, RC/128), 256, 0, stream>>>(
            act, w2b, offp, pair_token, out, r0);
    }
}